// Round 6
// baseline (29.914 us; speedup 1.0000x reference)
//
#include <hip/hip_runtime.h>

#define CC 16
#define OO 32
#define LL 65536   // 256*256

typedef __attribute__((ext_vector_type(8))) short bf16x8;
typedef __attribute__((ext_vector_type(4))) float f32x4;
typedef __attribute__((ext_vector_type(4))) int   i32x4;

static __device__ __forceinline__ ushort f2b(float f) {   // exact RNE (prepass)
    union { float f; unsigned u; } v; v.f = f;
    return (ushort)((v.u + 0x7fff + ((v.u >> 16) & 1)) >> 16);
}
// pack two floats -> (bf16(fh)<<16)|bf16(fl), round-half-up: proven in R2-R4
static __device__ __forceinline__ unsigned pk2(float fl, float fh) {
    unsigned ul = __float_as_uint(fl) + 0x8000u;
    unsigned uh = __float_as_uint(fh) + 0x8000u;
    return __builtin_amdgcn_perm(uh, ul, 0x07060302);
}

// ---- prepass: weights -> bf16 in exact MFMA A-fragment order (unchanged) ----
__global__ void prepass(const float* __restrict__ W1, const float* __restrict__ b1,
                        const float* __restrict__ W2, const float* __restrict__ b2,
                        const float* __restrict__ bias,
                        ushort* __restrict__ w1f, ushort* __restrict__ w2f) {
    int idx = blockIdx.x * 256 + threadIdx.x;
    if (idx < 5120) {
        int f = idx >> 9, lane = (idx >> 3) & 63, j = idx & 7;
        int ks = f >> 1, ot = f & 1, lm = lane & 15, g = lane >> 4;
        int o = ot * 16 + lm, kk = ks * 32 + g * 8 + j;
        int r = kk >> 4, c = kk & 15;
        float v = (kk < 144) ? W1[o * 144 + c * 9 + r] : (kk == 144 ? b1[o] : 0.f);
        w1f[idx] = f2b(v);
    } else if (idx < 15360) {
        int i2 = idx - 5120;
        int f = i2 >> 9, lane = (i2 >> 3) & 63, j = i2 & 7;
        int ks = f >> 1, ot = f & 1, lm = lane & 15, g = lane >> 4;
        int o = ot * 16 + lm, kk = ks * 32 + g * 8 + j;
        float v;
        if      (kk < 288) v = W2[o * 288 + kk];
        else if (kk < 297) v = b2[o * 9 + (kk - 288)];
        else if (kk == 297) v = bias[o];
        else               v = 0.f;
        w2f[i2] = f2b(v);
    }
}

// ---- main: 512 thr (8 waves), 1 row/block, grid 1024; W1 in regs, W2 in LDS ----
__global__ __launch_bounds__(512, 4) void dynaconv_mfma(
    const float* __restrict__ x, const ushort* __restrict__ w1f,
    const ushort* __restrict__ w2f, float* __restrict__ out)
{
    __shared__ __align__(16) ushort xs[3][258][24];   // 37,152 B
    __shared__ __align__(16) float  S[3][258];        //  3,096 B
    __shared__ __align__(16) ushort W2L[20 * 512];    // 20,480 B  (frag f: f*512 + lane*8)

    const int tid  = threadIdx.x;
    const int wv   = tid >> 6;
    const int lane = tid & 63;
    const int g    = lane >> 4;
    const int lm   = lane & 15;

    // XCD-chunked swizzle (1024 = 8*128, bijective)
    const int vbid = (blockIdx.x & 7) * 128 + (blockIdx.x >> 3);
    const int b    = vbid >> 8;
    const int h    = vbid & 255;

    // ---- W1 fragments -> regs (40 VGPR) ----
    bf16x8 W1R[10];
#pragma unroll
    for (int f = 0; f < 10; ++f) W1R[f] = *(const bf16x8*)(w1f + (f * 64 + lane) * 8);

    // ---- W2 fragments -> LDS (linear copy, 1280 x 16B) ----
    {
        const i32x4* src = (const i32x4*)w2f;
        i32x4*       dst = (i32x4*)W2L;
#pragma unroll
        for (int k = 0; k < 3; ++k) {
            int i = tid + k * 512;
            if (i < 1280) dst[i] = src[i];
        }
    }

    // ---- stage 3 rows x 256 cols x 16 ch -> bf16 LDS + fp32 channel sums ----
    const float* xb = x + b * (CC * LL);
    if (tid < 256) {            // waves 0-3: rows 0 (h-1) and 1 (h)
        const int hm = h - 1;
        const bool ok0 = hm >= 0;
        const int off0 = (ok0 ? hm : 0) * 256 + tid;
        const int off1 = h * 256 + tid;
        float s0 = 0.f, s1 = 0.f;
#pragma unroll
        for (int cp = 0; cp < 8; ++cp) {
            const float* p0 = xb + (2 * cp) * LL;
            const float* p1 = p0 + LL;
            float va0 = p0[off0], vb0 = p1[off0];
            va0 = ok0 ? va0 : 0.f; vb0 = ok0 ? vb0 : 0.f;
            float va1 = p0[off1], vb1 = p1[off1];
            s0 += va0 + vb0; s1 += va1 + vb1;
            *(unsigned*)&xs[0][tid + 1][2 * cp] = pk2(va0, vb0);
            *(unsigned*)&xs[1][tid + 1][2 * cp] = pk2(va1, vb1);
        }
        S[0][tid + 1] = s0; S[1][tid + 1] = s1;
    } else {                    // waves 4-7: row 2 (h+1)
        const int col = tid - 256;
        const int hp = h + 1;
        const bool ok2 = hp < 256;
        const int off2 = (ok2 ? hp : 0) * 256 + col;
        float s2 = 0.f;
#pragma unroll
        for (int cp = 0; cp < 8; ++cp) {
            const float* p0 = xb + (2 * cp) * LL;
            const float* p1 = p0 + LL;
            float va = p0[off2], vb = p1[off2];
            va = ok2 ? va : 0.f; vb = ok2 ? vb : 0.f;
            s2 += va + vb;
            *(unsigned*)&xs[2][col + 1][2 * cp] = pk2(va, vb);
        }
        S[2][col + 1] = s2;
    }
    if (tid < 96) { int r = tid >> 5, side = (tid >> 4) & 1, c = tid & 15; xs[r][side * 257][c] = 0; }
    if (tid < 6)  S[tid >> 1][(tid & 1) * 257] = 0.f;
    __syncthreads();   // the only barrier

    // per-ks feat LDS offsets (ushort units)
    int soff[5];
#pragma unroll
    for (int ks = 0; ks < 5; ++ks) {
        int r = 2 * ks + (g >> 1); if (r > 8) r = 8;
        int r3 = (r * 11) >> 5, rm = r - 3 * r3;
        soff[ks] = (r3 * 258 + rm + lm) * 24 + (g & 1) * 8;
    }
    const ushort* xsf = &xs[0][0][0];
    const int sA = ((g & 1) << 5) | lm;   // hid shuffle sources
    const int sB = sA + 16;
    const int hh = g >> 1;                // take hi half of packed word?

#pragma unroll
    for (int t = 0; t < 2; ++t) {
        const int w0t = wv * 32 + t * 16;
        const int tb = w0t * 24;

        // ---- phase 1: hid[o,pixel] = W1e @ feat ----
        f32x4 a1[2] = {{0.f,0.f,0.f,0.f},{0.f,0.f,0.f,0.f}};
#pragma unroll
        for (int ks = 0; ks < 5; ++ks) {
            bf16x8 ff = *(const bf16x8*)(xsf + soff[ks] + tb);
            if (ks == 4) {               // g>=2: bias-extension K block
                i32x4 wd = *(i32x4*)&ff;
                wd[0] = (g < 2) ? wd[0] : (g == 2 ? 0x3F80 : 0);
                wd[1] = (g < 2) ? wd[1] : 0;
                wd[2] = (g < 2) ? wd[2] : 0;
                wd[3] = (g < 2) ? wd[3] : 0;
                ff = *(bf16x8*)&wd;
            }
            a1[0] = __builtin_amdgcn_mfma_f32_16x16x32_bf16(W1R[2 * ks],     ff, a1[0], 0, 0, 0);
            a1[1] = __builtin_amdgcn_mfma_f32_16x16x32_bf16(W1R[2 * ks + 1], ff, a1[1], 0, 0, 0);
        }

        // ---- tanh -> packed bf16 words (pk2) -> cross-lane redistribute (no LDS) ----
        unsigned Wq[4];
#pragma unroll
        for (int q = 0; q < 4; ++q) {
            float e0 = __expf(2.f * a1[0][q]);
            float t0 = 1.f - 2.f / (e0 + 1.f);
            float e1 = __expf(2.f * a1[1][q]);
            float t1 = 1.f - 2.f / (e1 + 1.f);
            Wq[q] = pk2(t0, t1);          // lo = hid[o<16], hi = hid[o>=16]
        }
        float hf[8];
#pragma unroll
        for (int q = 0; q < 4; ++q) {
            unsigned pa = (unsigned)__shfl((int)Wq[q], sA);
            unsigned pb = (unsigned)__shfl((int)Wq[q], sB);
            hf[q]     = __uint_as_float(hh ? (pa & 0xffff0000u) : (pa << 16));
            hf[4 + q] = __uint_as_float(hh ? (pb & 0xffff0000u) : (pb << 16));
        }

        float pcv[9];
#pragma unroll
        for (int r = 0; r < 9; ++r) pcv[r] = S[r / 3][w0t + lm + (r % 3)];

        // ---- phase 2: out[o,pixel] = W2p @ (pc ⊗ hid), W2 frags from LDS ----
        f32x4 a2[2] = {{0.f,0.f,0.f,0.f},{0.f,0.f,0.f,0.f}};
#pragma unroll
        for (int ks = 0; ks < 9; ++ks) {
            const float p = pcv[ks];
            i32x4 wd;
            wd[0] = (int)pk2(hf[0] * p, hf[1] * p);
            wd[1] = (int)pk2(hf[2] * p, hf[3] * p);
            wd[2] = (int)pk2(hf[4] * p, hf[5] * p);
            wd[3] = (int)pk2(hf[6] * p, hf[7] * p);
            bf16x8 ff2 = *(bf16x8*)&wd;
            bf16x8 bm0 = *(const bf16x8*)(W2L + (2 * ks)     * 512 + lane * 8);
            bf16x8 bm1 = *(const bf16x8*)(W2L + (2 * ks + 1) * 512 + lane * 8);
            a2[0] = __builtin_amdgcn_mfma_f32_16x16x32_bf16(bm0, ff2, a2[0], 0, 0, 0);
            a2[1] = __builtin_amdgcn_mfma_f32_16x16x32_bf16(bm1, ff2, a2[1], 0, 0, 0);
        }
        {   // ks==9: K-extension block (b2·pc + bias)
            i32x4 wd;
            wd[0] = (g == 0) ? (int)pk2(pcv[0], pcv[1]) : ((g == 1) ? (int)pk2(pcv[8], 1.f) : 0);
            wd[1] = (g == 0) ? (int)pk2(pcv[2], pcv[3]) : 0;
            wd[2] = (g == 0) ? (int)pk2(pcv[4], pcv[5]) : 0;
            wd[3] = (g == 0) ? (int)pk2(pcv[6], pcv[7]) : 0;
            bf16x8 ff2 = *(bf16x8*)&wd;
            bf16x8 bm0 = *(const bf16x8*)(W2L + 18 * 512 + lane * 8);
            bf16x8 bm1 = *(const bf16x8*)(W2L + 19 * 512 + lane * 8);
            a2[0] = __builtin_amdgcn_mfma_f32_16x16x32_bf16(bm0, ff2, a2[0], 0, 0, 0);
            a2[1] = __builtin_amdgcn_mfma_f32_16x16x32_bf16(bm1, ff2, a2[1], 0, 0, 0);
        }

        // ---- stores straight from accumulator ----
        float* ob = out + b * (OO * LL) + h * 256 + w0t + lm;
#pragma unroll
        for (int ot = 0; ot < 2; ++ot)
#pragma unroll
            for (int q = 0; q < 4; ++q)
                ob[(ot * 16 + g * 4 + q) * LL] = a2[ot][q];
    }
}

extern "C" void kernel_launch(void* const* d_in, const int* in_sizes, int n_in,
                              void* d_out, int out_size, void* d_ws, size_t ws_size,
                              hipStream_t stream) {
    const float* x    = (const float*)d_in[0];
    const float* W1   = (const float*)d_in[1];
    const float* b1   = (const float*)d_in[2];
    const float* W2   = (const float*)d_in[3];
    const float* b2   = (const float*)d_in[4];
    const float* bias = (const float*)d_in[5];
    float* out = (float*)d_out;

    ushort* w1f = (ushort*)d_ws;        // 5120 bf16
    ushort* w2f = w1f + 5120;           // 10240 bf16

    prepass<<<60, 256, 0, stream>>>(W1, b1, W2, b2, bias, w1f, w2f);
    dynaconv_mfma<<<1024, 512, 0, stream>>>(x, w1f, w2f, out);
}